// Round 3
// baseline (217.630 us; speedup 1.0000x reference)
//
#include <hip/hip_runtime.h>
#include <math.h>

#define BB 4096
#define DD 128

typedef __attribute__((ext_vector_type(8))) short bf16x8;
typedef __attribute__((ext_vector_type(4))) float f32x4;

__device__ __forceinline__ unsigned fkey(float x){
    int b = __float_as_int(x);
    return (unsigned)(b ^ ((b >> 31) | 0x80000000));
}
__device__ __forceinline__ float funkey(unsigned u){
    unsigned b = (u & 0x80000000u) ? (u & 0x7fffffffu) : ~u;
    return __uint_as_float(b);
}

// ---------- block reductions (256 threads = 4 waves of 64) ----------
__device__ __forceinline__ float blkSumF(float v, volatile float* sh){
    #pragma unroll
    for (int o = 32; o > 0; o >>= 1) v += __shfl_down(v, o);
    int t = threadIdx.x;
    __syncthreads();
    if ((t & 63) == 0) sh[t >> 6] = v;
    __syncthreads();
    return (sh[0] + sh[1]) + (sh[2] + sh[3]);
}
__device__ __forceinline__ float blkMaxF(float v, volatile float* sh){
    #pragma unroll
    for (int o = 32; o > 0; o >>= 1) v = fmaxf(v, __shfl_down(v, o));
    int t = threadIdx.x;
    __syncthreads();
    if ((t & 63) == 0) sh[t >> 6] = v;
    __syncthreads();
    return fmaxf(fmaxf(sh[0], sh[1]), fmaxf(sh[2], sh[3]));
}
__device__ __forceinline__ int blkSumI(int v, volatile int* sh){
    #pragma unroll
    for (int o = 32; o > 0; o >>= 1) v += __shfl_down(v, o);
    int t = threadIdx.x;
    __syncthreads();
    if ((t & 63) == 0) sh[t >> 6] = v;
    __syncthreads();
    return (sh[0] + sh[1]) + (sh[2] + sh[3]);
}

// ---------- normalize -> bf16, stored with XOR-swizzled column ----------
__global__ void krn_normalize(const float* __restrict__ drug, const float* __restrict__ se,
                              ushort* __restrict__ Z){
    int row = blockIdx.x, br = blockIdx.y, t = threadIdx.x;  // blockDim = 128
    float dv = drug[row * DD + t];
    float sv = se[row * DD + t];
    float v = (br == 0) ? dv : ((br == 1) ? sv : dv * sv);
    float sq = v * v;
    #pragma unroll
    for (int o = 32; o > 0; o >>= 1) sq += __shfl_down(sq, o);
    __shared__ float sh[2];
    if ((t & 63) == 0) sh[t >> 6] = sq;
    __syncthreads();
    float nrm = sqrtf(sh[0] + sh[1]);
    float outv = v / fmaxf(nrm, 1e-12f);
    unsigned u = __float_as_uint(outv);
    unsigned r = (u + 0x7FFFu + ((u >> 16) & 1u)) >> 16;   // RNE bf16
    int col = t ^ ((row & 7) << 3);
    Z[((size_t)br * BB + row) * DD + col] = (ushort)r;
}

// ---------- negative-pair counting (label-only) ----------
__global__ void krn_init(int* __restrict__ ntot){ *ntot = 0; }

__global__ __launch_bounds__(256) void krn_negcount(const float* __restrict__ labels,
                                                    int* __restrict__ ntot){
    __shared__ float lab[BB];
    __shared__ int shi[4];
    int t = threadIdx.x;
    #pragma unroll
    for (int e = 0; e < 4; ++e)
        ((float4*)lab)[t + e * 256] = ((const float4*)labels)[t + e * 256];
    __syncthreads();
    int i0 = blockIdx.x * 16;
    int c = 0;
    for (int ii = 0; ii < 16; ++ii){
        float li = lab[i0 + ii];
        #pragma unroll
        for (int e = 0; e < 16; ++e){
            int j = t + e * 256;
            c += (fabsf(li - lab[j]) > 1.0f) ? 1 : 0;
        }
    }
    int cc = blkSumI(c, shi);
    if (t == 0) atomicAdd(ntot, cc);
}

__global__ void krn_calck(const int* __restrict__ ntot, int* __restrict__ kflags){
    int N = *ntot;
    int k = N >> 13;            // trunc((N/4096)*0.5), exact
    if (k < 1) k = 1;
    if (k > BB - 1) k = BB - 1;
    kflags[0] = k;
    kflags[1] = (N > 0) ? 1 : 0;
}

// ---------- bf16 MFMA GEMM: sim[z][slab x BB] = (Z_z Z_z^T)/T ----------
__device__ __forceinline__ bf16x8 frag_ld(const ushort* base, int row, int e0){
    int e = e0 ^ ((row & 7) << 3);
    return *(const bf16x8*)(base + row * DD + e);
}

__global__ __launch_bounds__(256) void krn_gemm(const ushort* __restrict__ Z,
                                                float* __restrict__ sim, size_t simStride,
                                                int r0){
    __shared__ ushort As[128 * DD];
    __shared__ ushort Bs[128 * DD];
    const ushort* Zb = Z + (size_t)blockIdx.z * (BB * DD);
    float* simz = sim + (size_t)blockIdx.z * simStride;
    int t = threadIdx.x;
    int rowbase = r0 + blockIdx.y * 128;
    int colbase = blockIdx.x * 128;

    {
        const float4* gA = (const float4*)(Zb + (size_t)rowbase * DD);
        const float4* gB = (const float4*)(Zb + (size_t)colbase * DD);
        float4* lA = (float4*)As;
        float4* lB = (float4*)Bs;
        #pragma unroll
        for (int it = 0; it < 8; ++it){
            lA[it * 256 + t] = gA[it * 256 + t];
            lB[it * 256 + t] = gB[it * 256 + t];
        }
    }
    __syncthreads();

    int wid = t >> 6, lane = t & 63;
    int wr = (wid >> 1) * 64, wc = (wid & 1) * 64;
    int fr = lane & 15, fq = lane >> 4;

    f32x4 acc[4][4];
    #pragma unroll
    for (int m = 0; m < 4; ++m)
        #pragma unroll
        for (int n = 0; n < 4; ++n)
            acc[m][n] = (f32x4){0.f, 0.f, 0.f, 0.f};

    #pragma unroll
    for (int ks = 0; ks < 4; ++ks){
        int e0 = ks * 32 + fq * 8;
        bf16x8 a0 = frag_ld(As, wr + 0 * 16 + fr, e0);
        bf16x8 a1 = frag_ld(As, wr + 1 * 16 + fr, e0);
        bf16x8 a2 = frag_ld(As, wr + 2 * 16 + fr, e0);
        bf16x8 a3 = frag_ld(As, wr + 3 * 16 + fr, e0);
        bf16x8 b0 = frag_ld(Bs, wc + 0 * 16 + fr, e0);
        bf16x8 b1 = frag_ld(Bs, wc + 1 * 16 + fr, e0);
        bf16x8 b2 = frag_ld(Bs, wc + 2 * 16 + fr, e0);
        bf16x8 b3 = frag_ld(Bs, wc + 3 * 16 + fr, e0);
        acc[0][0] = __builtin_amdgcn_mfma_f32_16x16x32_bf16(a0, b0, acc[0][0], 0, 0, 0);
        acc[0][1] = __builtin_amdgcn_mfma_f32_16x16x32_bf16(a0, b1, acc[0][1], 0, 0, 0);
        acc[0][2] = __builtin_amdgcn_mfma_f32_16x16x32_bf16(a0, b2, acc[0][2], 0, 0, 0);
        acc[0][3] = __builtin_amdgcn_mfma_f32_16x16x32_bf16(a0, b3, acc[0][3], 0, 0, 0);
        acc[1][0] = __builtin_amdgcn_mfma_f32_16x16x32_bf16(a1, b0, acc[1][0], 0, 0, 0);
        acc[1][1] = __builtin_amdgcn_mfma_f32_16x16x32_bf16(a1, b1, acc[1][1], 0, 0, 0);
        acc[1][2] = __builtin_amdgcn_mfma_f32_16x16x32_bf16(a1, b2, acc[1][2], 0, 0, 0);
        acc[1][3] = __builtin_amdgcn_mfma_f32_16x16x32_bf16(a1, b3, acc[1][3], 0, 0, 0);
        acc[2][0] = __builtin_amdgcn_mfma_f32_16x16x32_bf16(a2, b0, acc[2][0], 0, 0, 0);
        acc[2][1] = __builtin_amdgcn_mfma_f32_16x16x32_bf16(a2, b1, acc[2][1], 0, 0, 0);
        acc[2][2] = __builtin_amdgcn_mfma_f32_16x16x32_bf16(a2, b2, acc[2][2], 0, 0, 0);
        acc[2][3] = __builtin_amdgcn_mfma_f32_16x16x32_bf16(a2, b3, acc[2][3], 0, 0, 0);
        acc[3][0] = __builtin_amdgcn_mfma_f32_16x16x32_bf16(a3, b0, acc[3][0], 0, 0, 0);
        acc[3][1] = __builtin_amdgcn_mfma_f32_16x16x32_bf16(a3, b1, acc[3][1], 0, 0, 0);
        acc[3][2] = __builtin_amdgcn_mfma_f32_16x16x32_bf16(a3, b2, acc[3][2], 0, 0, 0);
        acc[3][3] = __builtin_amdgcn_mfma_f32_16x16x32_bf16(a3, b3, acc[3][3], 0, 0, 0);
    }

    const float invT = 1.0f / 0.07f;
    int srow0 = blockIdx.y * 128 + wr + fq * 4;
    int scol0 = colbase + wc + fr;
    #pragma unroll
    for (int m = 0; m < 4; ++m){
        #pragma unroll
        for (int n = 0; n < 4; ++n){
            f32x4 c = acc[m][n];
            #pragma unroll
            for (int j = 0; j < 4; ++j)
                simz[(size_t)(srow0 + m * 16 + j) * BB + scol0 + n * 16] = c[j] * invT;
        }
    }
}

// ---------- per-branch tail: exact top-k boundary + LSE + rowloss ----------
// Uniform histogram over fkey space [klo,khi], refined until the boundary
// bin holds <=48 candidates, then exact rank-select on the gathered list.
// Ties handled exactly via rfin * exp(kth - M).
__device__ __forceinline__ void branch_tail(
    const float (&s)[16], float Mb, float psimb, float PWS,
    int mode, int kk, unsigned negbits, unsigned posbits, unsigned selfbits,
    int t, int bi, int i, float* __restrict__ rowloss,
    int* hist, int* wsum, volatile float* redf,
    volatile unsigned* selb, volatile unsigned* sel2, int* cnt, unsigned* list)
{
    unsigned ukth = 0;
    int rfin = 0;

    if (mode == 0){
        unsigned klo = 0x3E7FFFFFu;   // fkey(-16.0f)
        unsigned khi = 0xC1800000u;   // fkey(+16.0f)
        int rp = kk;
        while (true){
            if (klo == khi){ ukth = klo; rfin = rp; break; }
            unsigned range = khi - klo;
            int sh = 22 - __clz(range);            // (32-clz)-10 -> bins <= 1024
            if (sh < 0) sh = 0;
            hist[t] = 0; hist[t + 256] = 0; hist[t + 512] = 0; hist[t + 768] = 0;
            __syncthreads();
            #pragma unroll
            for (int idx = 0; idx < 16; ++idx){
                if (negbits & (1u << idx)){
                    unsigned u = fkey(s[idx]);
                    if (u >= klo && u <= khi)
                        atomicAdd(&hist[(u - klo) >> sh], 1);
                }
            }
            __syncthreads();
            {
                int g = 255 - t;
                int h0 = hist[4*g], h1 = hist[4*g+1], h2 = hist[4*g+2], h3 = hist[4*g+3];
                int Sg = h0 + h1 + h2 + h3;
                int v = Sg;
                #pragma unroll
                for (int o = 1; o < 64; o <<= 1){
                    int u2 = __shfl_up(v, o);
                    if ((t & 63) >= o) v += u2;
                }
                if ((t & 63) == 63) wsum[t >> 6] = v;
                __syncthreads();
                int w = t >> 6;
                int pre = (w > 0 ? wsum[0] : 0) + (w > 1 ? wsum[1] : 0) + (w > 2 ? wsum[2] : 0);
                v += pre;                       // inclusive over groups >= g
                int ge = v - Sg;                // strictly-above-group count
                int a3 = ge + h3, a2 = a3 + h2, a1 = a2 + h1, a0 = a1 + h0;
                if (a0 - h0 < rp && rp <= a0){ selb[0] = 4u*g+0u; selb[1] = (unsigned)(a0-h0); selb[2] = (unsigned)h0; }
                if (a1 - h1 < rp && rp <= a1){ selb[0] = 4u*g+1u; selb[1] = (unsigned)(a1-h1); selb[2] = (unsigned)h1; }
                if (a2 - h2 < rp && rp <= a2){ selb[0] = 4u*g+2u; selb[1] = (unsigned)(a2-h2); selb[2] = (unsigned)h2; }
                if (a3 - h3 < rp && rp <= a3){ selb[0] = 4u*g+3u; selb[1] = (unsigned)(a3-h3); selb[2] = (unsigned)h3; }
            }
            __syncthreads();
            unsigned B = selb[0];
            int ae = (int)selb[1];
            int c  = (int)selb[2];
            rp -= ae;
            klo = klo + (B << sh);
            unsigned nhi = klo + ((1u << sh) - 1u);
            if (nhi < khi) khi = nhi;
            if (c <= 48){
                if (t == 0) *cnt = 0;
                __syncthreads();
                #pragma unroll
                for (int idx = 0; idx < 16; ++idx){
                    if (negbits & (1u << idx)){
                        unsigned u = fkey(s[idx]);
                        if (u >= klo && u <= khi){
                            int p = atomicAdd(cnt, 1);
                            list[p] = u;
                        }
                    }
                }
                __syncthreads();
                int cc = *cnt;
                if (t < cc){
                    unsigned kj = list[t];
                    int g2 = 0, e2 = 0;
                    for (int mm = 0; mm < cc; ++mm){
                        unsigned km = list[mm];
                        g2 += (km > kj) ? 1 : 0;
                        e2 += (km == kj) ? 1 : 0;
                    }
                    if (g2 < rp && rp <= g2 + e2){ sel2[0] = kj; sel2[1] = (unsigned)g2; }
                }
                __syncthreads();
                ukth = sel2[0];
                rfin = rp - (int)sel2[1];
                break;
            }
            __syncthreads();
        }
    }

    // denominator: sum exp(s - M) over denom mask
    float El = 0.f;
    if (mode == 2){
        #pragma unroll
        for (int idx = 0; idx < 16; ++idx)
            if (!(selfbits & (1u << idx))) El += __expf(s[idx] - Mb);
    } else if (mode == 1){
        unsigned em = negbits | posbits;
        #pragma unroll
        for (int idx = 0; idx < 16; ++idx)
            if (em & (1u << idx)) El += __expf(s[idx] - Mb);
    } else {
        #pragma unroll
        for (int idx = 0; idx < 16; ++idx){
            unsigned bit = 1u << idx;
            bool dm = (posbits & bit) != 0u;
            if (negbits & bit) dm = dm || (fkey(s[idx]) > ukth);
            if (dm) El += __expf(s[idx] - Mb);
        }
    }
    float Etot = blkSumF(El, redf);

    if (t == 0){
        if (mode == 0) Etot += (float)rfin * __expf(funkey(ukth) - Mb);
        float logE = __logf(Etot + 1e-8f);
        float w = (psimb - Mb * PWS) - PWS * logE;
        rowloss[bi * BB + i] = w / fmaxf(PWS, 1e-8f);
    }
}

// ---------- merged 3-branch per-row stats ----------
__global__ __launch_bounds__(256) void krn_stats(const float* __restrict__ sim, size_t simStride,
                                                 const float* __restrict__ labels,
                                                 const int* __restrict__ kflags,
                                                 float* __restrict__ rowloss, int r0){
    __shared__ int hist[1024];
    __shared__ int wsum[4];
    __shared__ float redf[4];
    __shared__ int redi[4];
    __shared__ unsigned selb[3];
    __shared__ unsigned sel2[2];
    __shared__ int cnt;
    __shared__ unsigned list[64];

    int t = threadIdx.x;
    int i = r0 + blockIdx.x;
    float li = labels[i];

    float s0[16], s1[16], s2[16];
    unsigned negbits = 0, posbits = 0, selfbits = 0;
    float m0 = -INFINITY, m1 = -INFINITY, m2 = -INFINITY;
    float pws = 0.f, ps0 = 0.f, ps1 = 0.f, ps2 = 0.f;
    int ncnt = 0;

    const float4* r0p = (const float4*)(sim + (size_t)blockIdx.x * BB);
    const float4* r1p = (const float4*)(sim + simStride + (size_t)blockIdx.x * BB);
    const float4* r2p = (const float4*)(sim + 2 * simStride + (size_t)blockIdx.x * BB);
    const float4* lab4 = (const float4*)labels;

    #pragma unroll
    for (int e = 0; e < 4; ++e){
        float4 v0 = r0p[t + e * 256];
        float4 v1 = r1p[t + e * 256];
        float4 v2 = r2p[t + e * 256];
        float4 lv = lab4[t + e * 256];
        float a0c[4] = {v0.x, v0.y, v0.z, v0.w};
        float a1c[4] = {v1.x, v1.y, v1.z, v1.w};
        float a2c[4] = {v2.x, v2.y, v2.z, v2.w};
        float llc[4] = {lv.x, lv.y, lv.z, lv.w};
        int jbase = (t + e * 256) * 4;
        #pragma unroll
        for (int c = 0; c < 4; ++c){
            int idx = e * 4 + c;
            float sv0 = a0c[c], sv1 = a1c[c], sv2 = a2c[c];
            s0[idx] = sv0; s1[idx] = sv1; s2[idx] = sv2;
            m0 = fmaxf(m0, sv0); m1 = fmaxf(m1, sv1); m2 = fmaxf(m2, sv2);
            float d = fabsf(li - llc[c]);
            int j = jbase + c;
            bool self = (j == i);
            if (self) selfbits |= 1u << idx;
            if (d > 1.0f){ negbits |= 1u << idx; ncnt++; }
            else if (!self && d < 0.34538776f) posbits |= 1u << idx;  // pw > 0.1
            if (!self){
                float pw = __expf(d * (-1.0f / 0.15f));
                pws += pw;
                ps0 += pw * sv0; ps1 += pw * sv1; ps2 += pw * sv2;
            }
        }
    }

    float M0 = blkMaxF(m0, redf);
    float M1 = blkMaxF(m1, redf);
    float M2 = blkMaxF(m2, redf);
    float P0 = blkSumF(ps0, redf);
    float P1 = blkSumF(ps1, redf);
    float P2 = blkSumF(ps2, redf);
    float PWS = blkSumF(pws, redf);
    int NC = blkSumI(ncnt, redi);

    int kk = kflags[0], anyneg = kflags[1];
    int mode = anyneg ? ((NC <= kk) ? 1 : 0) : 2;

    branch_tail(s0, M0, P0, PWS, mode, kk, negbits, posbits, selfbits,
                t, 0, i, rowloss, hist, wsum, redf, selb, sel2, &cnt, list);
    branch_tail(s1, M1, P1, PWS, mode, kk, negbits, posbits, selfbits,
                t, 1, i, rowloss, hist, wsum, redf, selb, sel2, &cnt, list);
    branch_tail(s2, M2, P2, PWS, mode, kk, negbits, posbits, selfbits,
                t, 2, i, rowloss, hist, wsum, redf, selb, sel2, &cnt, list);
}

// ---------- final deterministic reduction ----------
__global__ void krn_final(const float* __restrict__ rowloss, float* __restrict__ out){
    __shared__ float redf[4];
    int t = threadIdx.x;  // 256
    float total = 0.f;
    for (int b = 0; b < 3; ++b){
        float ssum = 0.f;
        for (int e = 0; e < 16; ++e) ssum += rowloss[b * BB + t + e * 256];
        float S = blkSumF(ssum, redf);
        total += S * (1.0f / BB);
    }
    if (t == 0) out[0] = -total / 3.0f;
}

extern "C" void kernel_launch(void* const* d_in, const int* in_sizes, int n_in,
                              void* d_out, int out_size, void* d_ws, size_t ws_size,
                              hipStream_t stream){
    const float* drug   = (const float*)d_in[0];
    const float* se     = (const float*)d_in[1];
    const float* labels = (const float*)d_in[2];
    float* out = (float*)d_out;
    char* ws = (char*)d_ws;

    const size_t zbytes = (size_t)3 * BB * DD * sizeof(ushort);    // 3 MB bf16
    const size_t tail   = (size_t)3 * BB * sizeof(float) + 256;

    int slab = BB;
    while (slab > 128 && zbytes + tail + (size_t)3 * slab * BB * sizeof(float) > ws_size)
        slab >>= 1;
    size_t simStride = (size_t)slab * BB;

    ushort* Z      = (ushort*)ws;
    float* simbuf  = (float*)(ws + zbytes);
    size_t off     = zbytes + (size_t)3 * simStride * sizeof(float);
    float* rowloss = (float*)(ws + off);  off += (size_t)3 * BB * sizeof(float);
    int*   ntot    = (int*)(ws + off);
    int*   kflags  = ntot + 2;

    krn_normalize<<<dim3(BB, 3), 128, 0, stream>>>(drug, se, Z);
    krn_init<<<1, 1, 0, stream>>>(ntot);
    krn_negcount<<<256, 256, 0, stream>>>(labels, ntot);
    krn_calck<<<1, 1, 0, stream>>>(ntot, kflags);

    int nslab = BB / slab;
    for (int s2 = 0; s2 < nslab; ++s2){
        krn_gemm<<<dim3(BB / 128, slab / 128, 3), 256, 0, stream>>>(Z, simbuf, simStride, s2 * slab);
        krn_stats<<<slab, 256, 0, stream>>>(simbuf, simStride, labels, kflags, rowloss, s2 * slab);
    }
    krn_final<<<1, 256, 0, stream>>>(rowloss, out);
}

// Round 4
// 166.728 us; speedup vs baseline: 1.3053x; 1.3053x over previous
//
#include <hip/hip_runtime.h>
#include <math.h>

#define BB 4096
#define DD 128
#define KLO 0x3E7FFFFFu     /* fkey(-16.0f) */
#define KHI 0xC1800000u     /* fkey(+16.0f) */
#define SH0 19              /* first-level bin shift: 4193 bins over [KLO,KHI] */
#define NBALLOC 4352        /* 17*256, zero-padded hist allocation */

typedef __attribute__((ext_vector_type(8))) short bf16x8;
typedef __attribute__((ext_vector_type(4))) float f32x4;

__device__ __forceinline__ unsigned fkey(float x){
    int b = __float_as_int(x);
    return (unsigned)(b ^ ((b >> 31) | 0x80000000));
}
__device__ __forceinline__ float funkey(unsigned u){
    unsigned b = (u & 0x80000000u) ? (u & 0x7fffffffu) : ~u;
    return __uint_as_float(b);
}

__device__ __forceinline__ float blkSumF(float v, volatile float* sh){
    #pragma unroll
    for (int o = 32; o > 0; o >>= 1) v += __shfl_down(v, o);
    int t = threadIdx.x;
    __syncthreads();
    if ((t & 63) == 0) sh[t >> 6] = v;
    __syncthreads();
    return (sh[0] + sh[1]) + (sh[2] + sh[3]);
}
__device__ __forceinline__ int blkSumI(int v, volatile int* sh){
    #pragma unroll
    for (int o = 32; o > 0; o >>= 1) v += __shfl_down(v, o);
    int t = threadIdx.x;
    __syncthreads();
    if ((t & 63) == 0) sh[t >> 6] = v;
    __syncthreads();
    return (sh[0] + sh[1]) + (sh[2] + sh[3]);
}

// ---------- normalize -> bf16, stored with XOR-swizzled column ----------
__global__ void krn_normalize(const float* __restrict__ drug, const float* __restrict__ se,
                              ushort* __restrict__ Z){
    int row = blockIdx.x, br = blockIdx.y, t = threadIdx.x;  // blockDim = 128
    float dv = drug[row * DD + t];
    float sv = se[row * DD + t];
    float v = (br == 0) ? dv : ((br == 1) ? sv : dv * sv);
    float sq = v * v;
    #pragma unroll
    for (int o = 32; o > 0; o >>= 1) sq += __shfl_down(sq, o);
    __shared__ float sh[2];
    if ((t & 63) == 0) sh[t >> 6] = sq;
    __syncthreads();
    float nrm = sqrtf(sh[0] + sh[1]);
    float outv = v / fmaxf(nrm, 1e-12f);
    unsigned u = __float_as_uint(outv);
    unsigned r = (u + 0x7FFFu + ((u >> 16) & 1u)) >> 16;   // RNE bf16
    int col = t ^ ((row & 7) << 3);
    Z[((size_t)br * BB + row) * DD + col] = (ushort)r;
}

// ---------- negative-pair counting (label-only) ----------
__global__ void krn_init(int* __restrict__ ntot){ *ntot = 0; }

__global__ __launch_bounds__(256) void krn_negcount(const float* __restrict__ labels,
                                                    int* __restrict__ ntot){
    __shared__ float lab[BB];
    __shared__ int shi[4];
    int t = threadIdx.x;
    #pragma unroll
    for (int e = 0; e < 4; ++e)
        ((float4*)lab)[t + e * 256] = ((const float4*)labels)[t + e * 256];
    __syncthreads();
    int i0 = blockIdx.x * 16;
    int c = 0;
    for (int ii = 0; ii < 16; ++ii){
        float li = lab[i0 + ii];
        #pragma unroll
        for (int e = 0; e < 16; ++e){
            int j = t + e * 256;
            c += (fabsf(li - lab[j]) > 1.0f) ? 1 : 0;
        }
    }
    int cc = blkSumI(c, shi);
    if (t == 0) atomicAdd(ntot, cc);
}

__global__ void krn_calck(const int* __restrict__ ntot, int* __restrict__ kflags){
    int N = *ntot;
    int k = N >> 13;            // trunc((N/4096)*0.5), exact
    if (k < 1) k = 1;
    if (k > BB - 1) k = BB - 1;
    kflags[0] = k;
    kflags[1] = (N > 0) ? 1 : 0;
}

// ---------- bf16 MFMA GEMM: sim[z][BB x BB] = (Z_z Z_z^T)/T ----------
__device__ __forceinline__ bf16x8 frag_ld(const ushort* base, int row, int e0){
    int e = e0 ^ ((row & 7) << 3);
    return *(const bf16x8*)(base + row * DD + e);
}

__global__ __launch_bounds__(256) void krn_gemm(const ushort* __restrict__ Z,
                                                float* __restrict__ sim, size_t simStride,
                                                int r0){
    __shared__ ushort As[128 * DD];
    __shared__ ushort Bs[128 * DD];
    const ushort* Zb = Z + (size_t)blockIdx.z * (BB * DD);
    float* simz = sim + (size_t)blockIdx.z * simStride;
    int t = threadIdx.x;
    int rowbase = r0 + blockIdx.y * 128;
    int colbase = blockIdx.x * 128;

    {
        const float4* gA = (const float4*)(Zb + (size_t)rowbase * DD);
        const float4* gB = (const float4*)(Zb + (size_t)colbase * DD);
        float4* lA = (float4*)As;
        float4* lB = (float4*)Bs;
        #pragma unroll
        for (int it = 0; it < 8; ++it){
            lA[it * 256 + t] = gA[it * 256 + t];
            lB[it * 256 + t] = gB[it * 256 + t];
        }
    }
    __syncthreads();

    int wid = t >> 6, lane = t & 63;
    int wr = (wid >> 1) * 64, wc = (wid & 1) * 64;
    int fr = lane & 15, fq = lane >> 4;

    f32x4 acc[4][4];
    #pragma unroll
    for (int m = 0; m < 4; ++m)
        #pragma unroll
        for (int n = 0; n < 4; ++n)
            acc[m][n] = (f32x4){0.f, 0.f, 0.f, 0.f};

    #pragma unroll
    for (int ks = 0; ks < 4; ++ks){
        int e0 = ks * 32 + fq * 8;
        bf16x8 a0 = frag_ld(As, wr + 0 * 16 + fr, e0);
        bf16x8 a1 = frag_ld(As, wr + 1 * 16 + fr, e0);
        bf16x8 a2 = frag_ld(As, wr + 2 * 16 + fr, e0);
        bf16x8 a3 = frag_ld(As, wr + 3 * 16 + fr, e0);
        bf16x8 b0 = frag_ld(Bs, wc + 0 * 16 + fr, e0);
        bf16x8 b1 = frag_ld(Bs, wc + 1 * 16 + fr, e0);
        bf16x8 b2 = frag_ld(Bs, wc + 2 * 16 + fr, e0);
        bf16x8 b3 = frag_ld(Bs, wc + 3 * 16 + fr, e0);
        acc[0][0] = __builtin_amdgcn_mfma_f32_16x16x32_bf16(a0, b0, acc[0][0], 0, 0, 0);
        acc[0][1] = __builtin_amdgcn_mfma_f32_16x16x32_bf16(a0, b1, acc[0][1], 0, 0, 0);
        acc[0][2] = __builtin_amdgcn_mfma_f32_16x16x32_bf16(a0, b2, acc[0][2], 0, 0, 0);
        acc[0][3] = __builtin_amdgcn_mfma_f32_16x16x32_bf16(a0, b3, acc[0][3], 0, 0, 0);
        acc[1][0] = __builtin_amdgcn_mfma_f32_16x16x32_bf16(a1, b0, acc[1][0], 0, 0, 0);
        acc[1][1] = __builtin_amdgcn_mfma_f32_16x16x32_bf16(a1, b1, acc[1][1], 0, 0, 0);
        acc[1][2] = __builtin_amdgcn_mfma_f32_16x16x32_bf16(a1, b2, acc[1][2], 0, 0, 0);
        acc[1][3] = __builtin_amdgcn_mfma_f32_16x16x32_bf16(a1, b3, acc[1][3], 0, 0, 0);
        acc[2][0] = __builtin_amdgcn_mfma_f32_16x16x32_bf16(a2, b0, acc[2][0], 0, 0, 0);
        acc[2][1] = __builtin_amdgcn_mfma_f32_16x16x32_bf16(a2, b1, acc[2][1], 0, 0, 0);
        acc[2][2] = __builtin_amdgcn_mfma_f32_16x16x32_bf16(a2, b2, acc[2][2], 0, 0, 0);
        acc[2][3] = __builtin_amdgcn_mfma_f32_16x16x32_bf16(a2, b3, acc[2][3], 0, 0, 0);
        acc[3][0] = __builtin_amdgcn_mfma_f32_16x16x32_bf16(a3, b0, acc[3][0], 0, 0, 0);
        acc[3][1] = __builtin_amdgcn_mfma_f32_16x16x32_bf16(a3, b1, acc[3][1], 0, 0, 0);
        acc[3][2] = __builtin_amdgcn_mfma_f32_16x16x32_bf16(a3, b2, acc[3][2], 0, 0, 0);
        acc[3][3] = __builtin_amdgcn_mfma_f32_16x16x32_bf16(a3, b3, acc[3][3], 0, 0, 0);
    }

    const float invT = 1.0f / 0.07f;
    int srow0 = blockIdx.y * 128 + wr + fq * 4;
    int scol0 = colbase + wc + fr;
    #pragma unroll
    for (int m = 0; m < 4; ++m){
        #pragma unroll
        for (int n = 0; n < 4; ++n){
            f32x4 c = acc[m][n];
            #pragma unroll
            for (int j = 0; j < 4; ++j)
                simz[(size_t)(srow0 + m * 16 + j) * BB + scol0 + n * 16] = c[j] * invT;
        }
    }
}

// ---------- per-(branch,row) stats: fused hist + exact select + LSE ----------
__global__ __launch_bounds__(256) void krn_stats(const float* __restrict__ sim, size_t simStride,
                                                 const float* __restrict__ labels,
                                                 const int* __restrict__ kflags,
                                                 float* __restrict__ rowloss, int r0){
    __shared__ int hist[NBALLOC];
    __shared__ int wsum[4];
    __shared__ float redm[4], reda[4], redb[4];
    __shared__ int redn[4];
    __shared__ float redf[4];
    __shared__ unsigned selb[3];
    __shared__ unsigned sel2[2];
    __shared__ int cnt;
    __shared__ unsigned list[64];

    int t = threadIdx.x;
    int bi = blockIdx.y;
    int i = r0 + blockIdx.x;
    float li = labels[i];

    #pragma unroll
    for (int e = 0; e < 17; ++e) hist[t + e * 256] = 0;
    __syncthreads();

    const float4* sp = (const float4*)(sim + (size_t)bi * simStride + (size_t)blockIdx.x * BB);
    const float4* lp = (const float4*)labels;

    float s[16];
    unsigned negbits = 0, posbits = 0, selfbits = 0;
    float m = -INFINITY, pws = 0.f, psim = 0.f;
    int ncnt = 0;

    // pass A: fused loads + label work + fixed-range neg histogram
    #pragma unroll
    for (int e = 0; e < 4; ++e){
        float4 sv = sp[t + e * 256];
        float4 lv = lp[t + e * 256];
        float sc[4] = {sv.x, sv.y, sv.z, sv.w};
        float lc[4] = {lv.x, lv.y, lv.z, lv.w};
        int jb = (t + e * 256) * 4;
        #pragma unroll
        for (int c = 0; c < 4; ++c){
            int idx = e * 4 + c;
            float v = sc[c];
            s[idx] = v;
            m = fmaxf(m, v);
            float d = fabsf(li - lc[c]);
            bool self = (jb + c == i);
            if (self) selfbits |= 1u << idx;
            if (d > 1.0f){
                negbits |= 1u << idx; ncnt++;
                atomicAdd(&hist[(fkey(v) - KLO) >> SH0], 1);
            } else if (!self && d < 0.34538776f){
                posbits |= 1u << idx;     // pw > 0.1
            }
            if (!self){
                float pw = __expf(d * (-1.0f / 0.15f));
                pws += pw;
                psim += pw * v;
            }
        }
    }

    // fused 4-quantity block reduction (single barrier pair)
    #pragma unroll
    for (int o = 32; o > 0; o >>= 1){
        m = fmaxf(m, __shfl_down(m, o));
        pws += __shfl_down(pws, o);
        psim += __shfl_down(psim, o);
        ncnt += __shfl_down(ncnt, o);
    }
    __syncthreads();   // also orders hist atomics before the scan below
    if ((t & 63) == 0){
        int w = t >> 6;
        redm[w] = m; reda[w] = pws; redb[w] = psim; redn[w] = ncnt;
    }
    __syncthreads();
    float M    = fmaxf(fmaxf(redm[0], redm[1]), fmaxf(redm[2], redm[3]));
    float PWS  = (reda[0] + reda[1]) + (reda[2] + reda[3]);
    float PSIM = (redb[0] + redb[1]) + (redb[2] + redb[3]);
    int   NC   = (redn[0] + redn[1]) + (redn[2] + redn[3]);

    int kk = kflags[0], anyneg = kflags[1];
    int mode = anyneg ? ((NC <= kk) ? 1 : 0) : 2;   // 0: top-k, 1: all negs, 2: self_mask

    unsigned ukth = 0;
    int rfin = 0;
    if (mode == 0){
        unsigned klo = KLO, khi = KHI;
        int sh = SH0;
        int rp = kk;
        bool ready = true;   // first-level hist pre-filled in pass A
        while (true){
            if (klo == khi){ ukth = klo; rfin = rp; break; }
            if (!ready){
                #pragma unroll
                for (int e = 0; e < 17; ++e) hist[t + e * 256] = 0;
                __syncthreads();
                #pragma unroll
                for (int idx = 0; idx < 16; ++idx){
                    if (negbits & (1u << idx)){
                        unsigned u = fkey(s[idx]);
                        if (u >= klo && u <= khi)
                            atomicAdd(&hist[(u - klo) >> sh], 1);
                    }
                }
                __syncthreads();
            }
            ready = false;
            // chunked suffix scan: thread t owns chunk g=255-t, bins [g*17, g*17+17)
            int g = 255 - t;
            int base = g * 17;
            int ls = 0;
            #pragma unroll
            for (int e = 0; e < 17; ++e) ls += hist[base + e];
            int v = ls;
            #pragma unroll
            for (int o = 1; o < 64; o <<= 1){
                int u2 = __shfl_up(v, o);
                if ((t & 63) >= o) v += u2;
            }
            if ((t & 63) == 63) wsum[t >> 6] = v;
            __syncthreads();
            int w = t >> 6;
            int pre = (w > 0 ? wsum[0] : 0) + (w > 1 ? wsum[1] : 0) + (w > 2 ? wsum[2] : 0);
            v += pre;                 // inclusive count over chunks >= g
            int aec = v - ls;         // strictly-above-chunk count
            if (aec < rp && rp <= v){
                int cum = aec;        // walk bins high -> low inside this chunk
                #pragma unroll
                for (int e = 16; e >= 0; --e){
                    int c = hist[base + e];
                    if (cum < rp && rp <= cum + c){
                        selb[0] = (unsigned)(base + e);
                        selb[1] = (unsigned)cum;
                        selb[2] = (unsigned)c;
                        break;
                    }
                    cum += c;
                }
            }
            __syncthreads();
            unsigned B = selb[0];
            int ae = (int)selb[1];
            int c  = (int)selb[2];
            rp -= ae;
            klo += B << sh;
            unsigned nhi = klo + ((1u << sh) - 1u);
            if (nhi < khi) khi = nhi;
            if (c <= 64){
                if (t == 0) cnt = 0;
                __syncthreads();
                #pragma unroll
                for (int idx = 0; idx < 16; ++idx){
                    if (negbits & (1u << idx)){
                        unsigned u = fkey(s[idx]);
                        if (u >= klo && u <= khi){
                            int p = atomicAdd(&cnt, 1);
                            list[p] = u;
                        }
                    }
                }
                __syncthreads();
                int cc = cnt;
                if (t < cc){
                    unsigned kj = list[t];
                    int g2 = 0, e2 = 0;
                    for (int mm = 0; mm < cc; ++mm){
                        unsigned km = list[mm];
                        g2 += (km > kj) ? 1 : 0;
                        e2 += (km == kj) ? 1 : 0;
                    }
                    if (g2 < rp && rp <= g2 + e2){ sel2[0] = kj; sel2[1] = (unsigned)g2; }
                }
                __syncthreads();
                ukth = sel2[0];
                rfin = rp - (int)sel2[1];
                break;
            }
            {   // refine: pick new shift so bins <= 4096
                unsigned range = khi - klo;
                int bits = 32 - __clz(range);
                sh = (bits > 12) ? (bits - 12) : 0;
            }
            __syncthreads();   // all selb/hist reads done before re-zero
        }
    }

    // denominator: sum exp(s - M) over denom mask (s held in registers)
    float El = 0.f;
    if (mode == 2){
        #pragma unroll
        for (int idx = 0; idx < 16; ++idx)
            if (!(selfbits & (1u << idx))) El += __expf(s[idx] - M);
    } else if (mode == 1){
        unsigned em = negbits | posbits;
        #pragma unroll
        for (int idx = 0; idx < 16; ++idx)
            if (em & (1u << idx)) El += __expf(s[idx] - M);
    } else {
        #pragma unroll
        for (int idx = 0; idx < 16; ++idx){
            unsigned bit = 1u << idx;
            bool dm = (posbits & bit) != 0u;
            if (negbits & bit) dm = dm || (fkey(s[idx]) > ukth);
            if (dm) El += __expf(s[idx] - M);
        }
    }
    float Etot = blkSumF(El, redf);

    if (t == 0){
        if (mode == 0) Etot += (float)rfin * __expf(funkey(ukth) - M);
        float logE = __logf(Etot + 1e-8f);
        float wl = (PSIM - M * PWS) - PWS * logE;
        rowloss[bi * BB + i] = wl / fmaxf(PWS, 1e-8f);
    }
}

// ---------- final deterministic reduction ----------
__global__ void krn_final(const float* __restrict__ rowloss, float* __restrict__ out){
    __shared__ float redf[4];
    int t = threadIdx.x;  // 256
    float total = 0.f;
    for (int b = 0; b < 3; ++b){
        float ssum = 0.f;
        for (int e = 0; e < 16; ++e) ssum += rowloss[b * BB + t + e * 256];
        float S = blkSumF(ssum, redf);
        total += S * (1.0f / BB);
    }
    if (t == 0) out[0] = -total / 3.0f;
}

extern "C" void kernel_launch(void* const* d_in, const int* in_sizes, int n_in,
                              void* d_out, int out_size, void* d_ws, size_t ws_size,
                              hipStream_t stream){
    const float* drug   = (const float*)d_in[0];
    const float* se     = (const float*)d_in[1];
    const float* labels = (const float*)d_in[2];
    float* out = (float*)d_out;
    char* ws = (char*)d_ws;

    const size_t zbytes = (size_t)3 * BB * DD * sizeof(ushort);    // 3 MB bf16
    const size_t tail   = (size_t)3 * BB * sizeof(float) + 256;

    int slab = BB;
    while (slab > 128 && zbytes + tail + (size_t)3 * slab * BB * sizeof(float) > ws_size)
        slab >>= 1;
    size_t simStride = (size_t)slab * BB;

    ushort* Z      = (ushort*)ws;
    float* simbuf  = (float*)(ws + zbytes);
    size_t off     = zbytes + (size_t)3 * simStride * sizeof(float);
    float* rowloss = (float*)(ws + off);  off += (size_t)3 * BB * sizeof(float);
    int*   ntot    = (int*)(ws + off);
    int*   kflags  = ntot + 2;

    krn_normalize<<<dim3(BB, 3), 128, 0, stream>>>(drug, se, Z);
    krn_init<<<1, 1, 0, stream>>>(ntot);
    krn_negcount<<<256, 256, 0, stream>>>(labels, ntot);
    krn_calck<<<1, 1, 0, stream>>>(ntot, kflags);

    int nslab = BB / slab;
    for (int s2 = 0; s2 < nslab; ++s2){
        krn_gemm<<<dim3(BB / 128, slab / 128, 3), 256, 0, stream>>>(Z, simbuf, simStride, s2 * slab);
        krn_stats<<<dim3(slab, 3), 256, 0, stream>>>(simbuf, simStride, labels, kflags, rowloss, s2 * slab);
    }
    krn_final<<<1, 256, 0, stream>>>(rowloss, out);
}